// Round 8
// baseline (385.027 us; speedup 1.0000x reference)
//
#include <hip/hip_runtime.h>

// Problem constants: b=4, t=16, n=m=2048, d=64
#define Bq 4
#define Tt 16
#define Nn 2048
#define Dd 64
#define EPSc 1e-4f

typedef __attribute__((ext_vector_type(4))) int intx4;   // i8-MFMA operand/acc

__device__ __forceinline__ int pack4i(int a, int b, int c, int d) {
    return (a & 255) | ((b & 255) << 8) | ((c & 255) << 16) | ((d & 255) << 24);
}

// async global->LDS, 16B per lane; LDS dest = wave-uniform base + lane*16
__device__ __forceinline__ void load_lds16(const void* gptr, void* lptr) {
    __builtin_amdgcn_global_load_lds(
        (const __attribute__((address_space(1))) unsigned int*)gptr,
        (__attribute__((address_space(3))) unsigned int*)lptr,
        16, 0, 0);
}

// stage an 8 KB block (128 rows x 64 B) with 8 waves: wave w copies 1 KB (1 DMA)
__device__ __forceinline__ void stage8k(const char* __restrict__ g, char* lds, int w, int l) {
    load_lds16(g + w * 1024 + l * 16, lds + w * 1024);
}

// ---------------------------------------------------------------------------
// convert: x,y (f32) -> per-row-scaled int8 hi/lo split, stored PRE-SWIZZLED:
//   byte index = row*64 + ((g ^ ((row>>1)&3))<<4) + within,  g = 16B k-chunk 0..3
//   a ~= s*ah + (s/254)*al,  s = rowmax/127, per-row scale arrays sxs/sys.
// Also exact row norms sqx/sqy, zero f/g t=0 slots, parity-0 pmin ([B][4][N])
// = -norm (encodes f_prev = g_prev = 0), zero loss accumulator. grid: 4096x256
// ---------------------------------------------------------------------------
__global__ void convert_kernel(const float* __restrict__ x, const float* __restrict__ y,
                               char* __restrict__ qxh, char* __restrict__ qxl,
                               char* __restrict__ qyh, char* __restrict__ qyl,
                               float* __restrict__ sxs, float* __restrict__ sys,
                               float* __restrict__ sqx, float* __restrict__ sqy,
                               float* __restrict__ pf0, float* __restrict__ pg0,
                               float* __restrict__ out_f, float* __restrict__ out_g,
                               float* __restrict__ loss_ws)
{
    const int tid = threadIdx.x;
    const int l = tid & 63;
    const int row = blockIdx.x * 32 + (tid >> 6) * 8 + (l >> 3);
    const int q = l & 7;                                 // 8-float group in row
    const int g = q >> 1;                                // 16-byte chunk
    const int sw = (row >> 1) & 3;
    const size_t dstb = (size_t)row * 64 + ((g ^ sw) << 4) + (q & 1) * 8;

    // ---------- x ----------
    const float4* px = reinterpret_cast<const float4*>(x + (size_t)row * 64 + q * 8);
    float4 u0 = px[0], u1 = px[1];
    float fx[8] = {u0.x, u0.y, u0.z, u0.w, u1.x, u1.y, u1.z, u1.w};
    float ssx = 0.f, amx = 0.f;
#pragma unroll
    for (int e = 0; e < 8; ++e) {
        ssx = fmaf(fx[e], fx[e], ssx);
        amx = fmaxf(amx, fabsf(fx[e]));
    }
#pragma unroll
    for (int d = 1; d < 8; d <<= 1) {
        ssx += __shfl_xor(ssx, d, 64);
        amx = fmaxf(amx, __shfl_xor(amx, d, 64));
    }
    amx = fmaxf(amx, 1e-8f);
    const float s1x = amx * (1.f / 127.f);
    const float i1x = 127.f / amx;
    const float i2x = i1x * 254.f;
    int ih[8], il[8];
#pragma unroll
    for (int e = 0; e < 8; ++e) {
        float hq = rintf(fx[e] * i1x);
        hq = fminf(fmaxf(hq, -127.f), 127.f);
        ih[e] = (int)hq;
        const float r = fmaf(-s1x, hq, fx[e]);
        float lq = rintf(r * i2x);
        lq = fminf(fmaxf(lq, -127.f), 127.f);
        il[e] = (int)lq;
    }
    *reinterpret_cast<int2*>(qxh + dstb) = make_int2(pack4i(ih[0], ih[1], ih[2], ih[3]),
                                                    pack4i(ih[4], ih[5], ih[6], ih[7]));
    *reinterpret_cast<int2*>(qxl + dstb) = make_int2(pack4i(il[0], il[1], il[2], il[3]),
                                                    pack4i(il[4], il[5], il[6], il[7]));

    // ---------- y ----------
    const float4* py = reinterpret_cast<const float4*>(y + (size_t)row * 64 + q * 8);
    float4 v0 = py[0], v1 = py[1];
    float fy[8] = {v0.x, v0.y, v0.z, v0.w, v1.x, v1.y, v1.z, v1.w};
    float ssy = 0.f, amy = 0.f;
#pragma unroll
    for (int e = 0; e < 8; ++e) {
        ssy = fmaf(fy[e], fy[e], ssy);
        amy = fmaxf(amy, fabsf(fy[e]));
    }
#pragma unroll
    for (int d = 1; d < 8; d <<= 1) {
        ssy += __shfl_xor(ssy, d, 64);
        amy = fmaxf(amy, __shfl_xor(amy, d, 64));
    }
    amy = fmaxf(amy, 1e-8f);
    const float s1y = amy * (1.f / 127.f);
    const float i1y = 127.f / amy;
    const float i2y = i1y * 254.f;
#pragma unroll
    for (int e = 0; e < 8; ++e) {
        float hq = rintf(fy[e] * i1y);
        hq = fminf(fmaxf(hq, -127.f), 127.f);
        ih[e] = (int)hq;
        const float r = fmaf(-s1y, hq, fy[e]);
        float lq = rintf(r * i2y);
        lq = fminf(fmaxf(lq, -127.f), 127.f);
        il[e] = (int)lq;
    }
    *reinterpret_cast<int2*>(qyh + dstb) = make_int2(pack4i(ih[0], ih[1], ih[2], ih[3]),
                                                    pack4i(ih[4], ih[5], ih[6], ih[7]));
    *reinterpret_cast<int2*>(qyl + dstb) = make_int2(pack4i(il[0], il[1], il[2], il[3]),
                                                    pack4i(il[4], il[5], il[6], il[7]));

    if (q == 0) {
        sxs[row] = s1x;
        sys[row] = s1y;
        sqx[row] = ssx;
        sqy[row] = ssy;
        const int t = (row >> 11) & 15, b = row >> 15, n = row & (Nn - 1);
        if (t == 0) {
            out_f[(size_t)b * Tt * Nn + n] = 0.f;
            out_g[(size_t)b * Tt * Nn + n] = 0.f;
#pragma unroll
            for (int h = 0; h < 4; ++h) {
                pf0[((size_t)b * 4 + h) * Nn + n] = -ssx;
                pg0[((size_t)b * 4 + h) * Nn + n] = -ssy;
            }
        }
    }
    if (blockIdx.x == 0 && tid < Tt) loss_ws[tid] = 0.f;
}

// per-tile body: ds_read B frags, 3 i8-MFMAs, integer-combine + min epilogue
#define COMPUTE_TILE(T, P)                                                      \
    {                                                                           \
        intx4 bhr[2], blr[2];                                                   \
        const int rb0 = (n0 + r15) * 64 + csel;                                 \
        const int rb1 = (n0 + 16 + r15) * 64 + csel;                            \
        bhr[0] = *reinterpret_cast<const intx4*>(&Bh[P][rb0]);                  \
        blr[0] = *reinterpret_cast<const intx4*>(&Bl[P][rb0]);                  \
        bhr[1] = *reinterpret_cast<const intx4*>(&Bh[P][rb1]);                  \
        blr[1] = *reinterpret_cast<const intx4*>(&Bl[P][rb1]);                  \
        intx4 acc1[4][2], acc2[4][2];                                           \
        _Pragma("unroll") for (int m = 0; m < 4; ++m)                           \
            _Pragma("unroll") for (int nn = 0; nn < 2; ++nn) {                  \
                acc1[m][nn] = intx4{0, 0, 0, 0};                                \
                acc2[m][nn] = intx4{0, 0, 0, 0};                                \
            }                                                                   \
        _Pragma("unroll") for (int m = 0; m < 4; ++m)                           \
            _Pragma("unroll") for (int nn = 0; nn < 2; ++nn) {                  \
                acc1[m][nn] = __builtin_amdgcn_mfma_i32_16x16x64_i8(            \
                    ahr[m], bhr[nn], acc1[m][nn], 0, 0, 0);                     \
                acc2[m][nn] = __builtin_amdgcn_mfma_i32_16x16x64_i8(            \
                    ahr[m], blr[nn], acc2[m][nn], 0, 0, 0);                     \
                acc2[m][nn] = __builtin_amdgcn_mfma_i32_16x16x64_i8(            \
                    alr[m], bhr[nn], acc2[m][nn], 0, 0, 0);                     \
            }                                                                   \
        const int jt = (T) * 128 + n0;                                          \
        const float cv0 = carr[jt + r15];                                       \
        const float cv1 = carr[jt + 16 + r15];                                  \
        const float tm0 = tarr[jt + r15];                                       \
        const float tm1 = tarr[jt + 16 + r15];                                  \
        _Pragma("unroll") for (int m = 0; m < 4; ++m) {                         \
            const float* sr = reinterpret_cast<const float*>(&srow4[m]);        \
            _Pragma("unroll") for (int r2 = 0; r2 < 4; ++r2) {                  \
                const int c0 = acc1[m][0][r2] * 254 + acc2[m][0][r2];           \
                const int c1 = acc1[m][1][r2] * 254 + acc2[m][1][r2];           \
                const float v0 = fmaf(sr[r2] * tm0, (float)c0, cv0);            \
                const float v1 = fmaf(sr[r2] * tm1, (float)c1, cv1);            \
                mm[m][r2] = fminf(mm[m][r2], fminf(v0, v1));                    \
            }                                                                   \
        }                                                                       \
    }

// ---------------------------------------------------------------------------
// minmat: fused f/g distance-min step, i8 hi/lo MFMA, 2 blocks/CU.
// grid 512 x 512 (8 waves). Block = (z = XCD slot, 128-row i-strip,
// 512-col j-quarter); 4 B-tiles, triple-buffered, depth-2 prefetch with
// counted vmcnt (4/4/2/0). dot = s_i*t_j/254 * (254*P1 + P2) (exact int).
// Finisher for step s-1 at kernel end (lanes 0..15, 16 rows per block).
// ---------------------------------------------------------------------------
__launch_bounds__(512, 2)
__global__ void minmat_kernel(const char* __restrict__ qxh, const char* __restrict__ qxl,
                              const char* __restrict__ qyh, const char* __restrict__ qyl,
                              const float* __restrict__ sxs, const float* __restrict__ sys,
                              const float* __restrict__ loga, const float* __restrict__ logb,
                              const float* __restrict__ sqx, const float* __restrict__ sqy,
                              const float* __restrict__ pf_in, const float* __restrict__ pg_in,
                              float* __restrict__ pf_out, float* __restrict__ pg_out,
                              float* __restrict__ out_f, float* __restrict__ out_g,
                              float* __restrict__ loss_ws, int s)
{
    __shared__ __align__(16) char Ah[8192], Al[8192];        // 16 KB
    __shared__ __align__(16) char Bh[3][8192], Bl[3][8192];  // 48 KB
    __shared__ __align__(16) float carr[512];                // c_j
    __shared__ __align__(16) float tarr[512];                // -2*t_j/254
    __shared__ __align__(16) float sarr[128];                // s_i
    __shared__ float redm[512];

    const int tid = threadIdx.x;
    const int w = tid >> 6, l = tid & 63;
    const int flat = blockIdx.x;
    const int z = flat & 7;                          // -> XCD (round-robin)
    const int b = z >> 1;
    const int which = (z & 1) ^ (s & 1);             // 0: f-update, 1: g-update
    const int rr0 = flat >> 3;                       // 0..63
    const int i0 = (rr0 & 15) * 128;
    const int jq = rr0 >> 4;                         // 0..3
    const int jbase = jq * 512;

    const size_t curm = ((size_t)b * Tt + s) * Nn;
    const size_t prvm = curm - Nn;

    const char* Ahs = (which ? qyh : qxh) + (curm + i0) * 64;
    const char* Als = (which ? qyl : qxl) + (curm + i0) * 64;
    const char* Bhs = (which ? qxh : qyh) + (prvm + jbase) * 64;
    const char* Bls = (which ? qxl : qyl) + (prvm + jbase) * 64;
    const float* ascale = (which ? sys : sxs) + curm + i0;
    const float* bscale = (which ? sxs : sys) + prvm + jbase;
    const float* pin  = which ? pf_in : pg_in;
    float* pout       = which ? pg_out : pf_out;
    const float* clog = (which ? loga : logb) + prvm + jbase;

    // ---- scalar global loads FIRST (oldest in vmcnt queue: their waits
    //      won't drain the DMAs issued below) ----
    const int jj = tid;                              // 0..511
    const float p0 = pin[((size_t)b * 4 + 0) * Nn + jbase + jj];
    const float p1 = pin[((size_t)b * 4 + 1) * Nn + jbase + jj];
    const float p2 = pin[((size_t)b * 4 + 2) * Nn + jbase + jj];
    const float p3 = pin[((size_t)b * 4 + 3) * Nn + jbase + jj];
    const float lg = clog[jj];
    const float bs = bscale[jj];
    float as_ = 0.f;
    if (tid < 128) as_ = ascale[tid];

    // ---- DMA prologue: A strip + B tiles 0,1 (6 DMAs/wave) ----
    stage8k(Ahs, Ah, w, l);
    stage8k(Als, Al, w, l);
    stage8k(Bhs, Bh[0], w, l);
    stage8k(Bls, Bl[0], w, l);
    stage8k(Bhs + 8192, Bh[1], w, l);
    stage8k(Bls + 8192, Bl[1], w, l);

    // ---- LDS scalar arrays ----
    carr[jj] = -fminf(fminf(p0, p1), fminf(p2, p3)) - EPSc * lg;
    tarr[jj] = bs * (-2.f / 254.f);
    if (tid < 128) sarr[tid] = as_;
    asm volatile("s_waitcnt lgkmcnt(0)" ::: "memory");
    __builtin_amdgcn_s_barrier();

    // ---- wave tile coords: 2x4 waves, 64 rows x 32 cols each ----
    const int wr = w >> 2, wc = w & 3;
    const int m0 = wr * 64, n0 = wc * 32;
    const int r15 = l & 15, g = l >> 4;
    const int csel = ((g ^ ((r15 >> 1) & 3)) << 4);  // swizzled 16B chunk

    float mm[4][4];
#pragma unroll
    for (int m = 0; m < 4; ++m)
#pragma unroll
        for (int r2 = 0; r2 < 4; ++r2) mm[m][r2] = 1e30f;

    intx4 ahr[4], alr[4];
    float4 srow4[4];

    // ================= tile 0 (buf 0) =================
    stage8k(Bhs + (size_t)2 * 8192, Bh[2], w, l);
    stage8k(Bls + (size_t)2 * 8192, Bl[2], w, l);
    asm volatile("s_waitcnt vmcnt(4)" ::: "memory"); // A + B0 landed
    __builtin_amdgcn_s_barrier();

    // hoist A fragments + row scales (A landed with B0)
#pragma unroll
    for (int m = 0; m < 4; ++m) {
        const int ra = (m0 + m * 16 + r15) * 64 + csel;
        ahr[m] = *reinterpret_cast<const intx4*>(&Ah[ra]);
        alr[m] = *reinterpret_cast<const intx4*>(&Al[ra]);
    }
#pragma unroll
    for (int m = 0; m < 4; ++m)
        srow4[m] = *reinterpret_cast<const float4*>(&sarr[m0 + m * 16 + g * 4]);

    COMPUTE_TILE(0, 0)
    __builtin_amdgcn_s_barrier();

    // ================= tile 1 (buf 1) =================
    stage8k(Bhs + (size_t)3 * 8192, Bh[0], w, l);    // tile 3 -> buf 0 (freed)
    stage8k(Bls + (size_t)3 * 8192, Bl[0], w, l);
    asm volatile("s_waitcnt vmcnt(4)" ::: "memory"); // B1 landed
    __builtin_amdgcn_s_barrier();
    COMPUTE_TILE(1, 1)
    __builtin_amdgcn_s_barrier();

    // ================= tile 2 (buf 2) =================
    asm volatile("s_waitcnt vmcnt(2)" ::: "memory"); // B2 landed
    __builtin_amdgcn_s_barrier();
    COMPUTE_TILE(2, 2)
    __builtin_amdgcn_s_barrier();

    // ================= tile 3 (buf 0) =================
    asm volatile("s_waitcnt vmcnt(0)" ::: "memory"); // B3 landed
    __builtin_amdgcn_s_barrier();
    COMPUTE_TILE(3, 0)

    // ---- once-per-dispatch reduce: 16 lanes (cols) -> rows ----
#pragma unroll
    for (int off = 1; off < 16; off <<= 1)
#pragma unroll
        for (int m = 0; m < 4; ++m)
#pragma unroll
            for (int r2 = 0; r2 < 4; ++r2)
                mm[m][r2] = fminf(mm[m][r2], __shfl_xor(mm[m][r2], off, 64));

    __syncthreads();                                 // redm region safe
    if (r15 == 0) {
#pragma unroll
        for (int m = 0; m < 4; ++m)
#pragma unroll
            for (int r2 = 0; r2 < 4; ++r2)
                redm[wc * 128 + m0 + m * 16 + g * 4 + r2] = mm[m][r2];
    }
    __syncthreads();
    if (tid < 128) {
        const float v = fminf(fminf(redm[tid], redm[128 + tid]),
                              fminf(redm[256 + tid], redm[384 + tid]));
        pout[((size_t)b * 4 + jq) * Nn + i0 + tid] = v;
    }

    // ---- finisher for step s-1 (16 rows per block) ----
    if (s >= 2 && tid < 16) {
        const int fr = flat * 16 + tid;              // 0..8191
        const int fb = fr >> 11, fi = fr & (Nn - 1);
        const size_t fidx = ((size_t)fb * Tt + (s - 1)) * Nn + fi;
        float mf = pf_in[((size_t)fb * 4 + 0) * Nn + fi];
        float mg = pg_in[((size_t)fb * 4 + 0) * Nn + fi];
#pragma unroll
        for (int h = 1; h < 4; ++h) {
            mf = fminf(mf, pf_in[((size_t)fb * 4 + h) * Nn + fi]);
            mg = fminf(mg, pg_in[((size_t)fb * 4 + h) * Nn + fi]);
        }
        const float fn = sqx[fidx] + mf, gn = sqy[fidx] + mg;
        out_f[fidx] = fn;
        out_g[fidx] = gn;
        float contrib = expf(loga[fidx]) * (fn + gn);
#pragma unroll
        for (int off = 8; off > 0; off >>= 1)
            contrib += __shfl_down(contrib, off, 64);
        if (tid == 0) atomicAdd(&loss_ws[s - 1], contrib);
    }
}

// ---------------------------------------------------------------------------
// standalone finish for the last step (u = 15). grid: 16 x 512
// ---------------------------------------------------------------------------
__global__ void finish_kernel(int u,
                              const float* __restrict__ pf, const float* __restrict__ pg,
                              const float* __restrict__ sqx, const float* __restrict__ sqy,
                              const float* __restrict__ loga,
                              float* __restrict__ out_f, float* __restrict__ out_g,
                              float* __restrict__ loss_ws)
{
    __shared__ float red8[8];
    const int tid = threadIdx.x;
    const int r = blockIdx.x * 512 + tid;            // 0 .. B*N-1
    const int b = r >> 11, i = r & (Nn - 1);
    const size_t idx = ((size_t)b * Tt + u) * Nn + i;
    float mf = pf[((size_t)b * 4 + 0) * Nn + i];
    float mg = pg[((size_t)b * 4 + 0) * Nn + i];
#pragma unroll
    for (int h = 1; h < 4; ++h) {
        mf = fminf(mf, pf[((size_t)b * 4 + h) * Nn + i]);
        mg = fminf(mg, pg[((size_t)b * 4 + h) * Nn + i]);
    }
    const float fn = sqx[idx] + mf, gn = sqy[idx] + mg;
    out_f[idx] = fn;
    out_g[idx] = gn;
    float contrib = expf(loga[idx]) * (fn + gn);
#pragma unroll
    for (int off = 32; off > 0; off >>= 1)
        contrib += __shfl_down(contrib, off, 64);
    if ((tid & 63) == 0) red8[tid >> 6] = contrib;
    __syncthreads();
    if (tid == 0) {
        float ssum = 0.f;
#pragma unroll
        for (int k = 0; k < 8; ++k) ssum += red8[k];
        atomicAdd(&loss_ws[u], ssum);
    }
}

// ---------------------------------------------------------------------------
// final: losses[b][t] = (t==0) ? 0 : loss_ws[t]
// ---------------------------------------------------------------------------
__global__ void final_kernel(float* __restrict__ out_losses, const float* __restrict__ loss_ws)
{
    const int tid = threadIdx.x;                    // 64 threads
    const int t = tid & 15;
    out_losses[tid] = (t == 0) ? 0.f : loss_ws[t];
}

extern "C" void kernel_launch(void* const* d_in, const int* in_sizes, int n_in,
                              void* d_out, int out_size, void* d_ws, size_t ws_size,
                              hipStream_t stream)
{
    const float* x    = (const float*)d_in[0];   // (4,16,2048,64)
    const float* y    = (const float*)d_in[1];   // (4,16,2048,64)
    const float* loga = (const float*)d_in[2];   // (4,16,2048)
    const float* logb = (const float*)d_in[3];   // (4,16,2048)

    float* out        = (float*)d_out;
    float* out_losses = out;                         // 4*16
    float* out_f      = out + Bq * Tt;               // 4*16*2048
    float* out_g      = out_f + (size_t)Bq * Tt * Nn;

    // workspace layout (~37 MB)
    const size_t NROW = (size_t)Bq * Tt * Nn;        // 131072 rows
    char* base = (char*)d_ws;
    char* qxh = base;                                // NROW*64 bytes each
    char* qxl = qxh + NROW * 64;
    char* qyh = qxl + NROW * 64;
    char* qyl = qyh + NROW * 64;
    float* sxs = (float*)(qyl + NROW * 64);          // NROW floats each
    float* sys = sxs + NROW;
    float* sqx = sys + NROW;
    float* sqy = sqx + NROW;
    const size_t PM = (size_t)Bq * 4 * Nn;           // pmin: [B][4][N]
    float* pf0 = sqy + NROW;
    float* pg0 = pf0 + PM;
    float* pf1 = pg0 + PM;
    float* pg1 = pf1 + PM;
    float* loss_ws = pg1 + PM;                       // T

    convert_kernel<<<4096, 256, 0, stream>>>(x, y, qxh, qxl, qyh, qyl,
                                             sxs, sys, sqx, sqy, pf0, pg0,
                                             out_f, out_g, loss_ws);

    for (int s = 1; s < Tt; ++s) {
        const float* pf_in = (s & 1) ? pf0 : pf1;
        const float* pg_in = (s & 1) ? pg0 : pg1;
        float* pf_out = (s & 1) ? pf1 : pf0;
        float* pg_out = (s & 1) ? pg1 : pg0;
        minmat_kernel<<<512, 512, 0, stream>>>(qxh, qxl, qyh, qyl, sxs, sys,
                                               loga, logb, sqx, sqy,
                                               pf_in, pg_in, pf_out, pg_out,
                                               out_f, out_g, loss_ws, s);
    }
    finish_kernel<<<16, 512, 0, stream>>>(15, pf1, pg1, sqx, sqy, loga,
                                          out_f, out_g, loss_ws);
    final_kernel<<<1, 64, 0, stream>>>(out_losses, loss_ws);
}